// Round 5
// baseline (371.302 us; speedup 1.0000x reference)
//
#include <hip/hip_runtime.h>
#include <hip/hip_cooperative_groups.h>
#include <stdint.h>

namespace cg = cooperative_groups;

#define NROWS 4096
#define DIM   512
#define EPS_COS 1e-8f
#define EPS_W   1e-6f
#define BT     256                 // output tile: BT x BT
#define NTILE  (NROWS / BT)        // 16
#define BK32   32
#define NSTEP2 (DIM / BK32)        // 16
#define NKSTEP (DIM / 64)          // 8 (fallback kernels)

typedef unsigned short ushort_t;
typedef __attribute__((ext_vector_type(8))) short   short8;
typedef __attribute__((ext_vector_type(8))) unsigned short ushort8;
typedef __attribute__((ext_vector_type(4))) float   floatx4;

// ---------- helpers ----------
__device__ inline ushort_t f2bf(float x) {            // RNE float->bf16
    unsigned u = __float_as_uint(x);
    unsigned r = (u + 0x7FFFu + ((u >> 16) & 1u)) >> 16;
    return (ushort_t)r;
}
__device__ inline float bf2f(ushort_t u) {
    return __uint_as_float(((unsigned)u) << 16);
}
// monotone float<->uint mapping for atomicMin/Max on floats
__device__ inline unsigned fmap(float f) {
    unsigned u = __float_as_uint(f);
    return (u & 0x80000000u) ? ~u : (u | 0x80000000u);
}
__device__ inline float funmap(unsigned u) {
    return __uint_as_float((u & 0x80000000u) ? (u & 0x7fffffffu) : ~u);
}

__device__ inline void gload_lds16(const void* g, void* l) {
    auto* gp = reinterpret_cast<const __attribute__((address_space(1))) unsigned int*>(
        reinterpret_cast<uintptr_t>(g));
    auto* lp = reinterpret_cast<__attribute__((address_space(3))) unsigned int*>(
        reinterpret_cast<uintptr_t>(l));
    __builtin_amdgcn_global_load_lds(gp, lp, 16, 0, 0);
}

// ======== BK=32 machinery (fused kernel) ========
// 256x32 bf16 tile (64 B rows). LDS[r][p] holds logical 16B-chunk p ^ ((r>>1)&3).
// Start banks over 8 rows: {0,16,4,20,8,24,12,28} -> conflict-free minimum.
__device__ __forceinline__ void stage32(const ushort_t* __restrict__ gbase,
                                        ushort_t* lds, int wave, int lane) {
#pragma unroll
    for (int q = 0; q < 2; q++) {
        int row0 = wave * 32 + q * 16;                // 8 waves cover 256 rows
        int lrow = row0 + (lane >> 2);
        int gchunk = (lane & 3) ^ ((lrow >> 1) & 3);
        gload_lds16(gbase + (size_t)lrow * DIM + gchunk * 8, lds + row0 * BK32);
    }
}
__device__ __forceinline__ short8 read_frag32(const ushort_t* tile, int fr, int lane) {
    int r = fr * 16 + (lane & 15);
    int p = (lane >> 4) ^ ((r >> 1) & 3);
    return *reinterpret_cast<const short8*>(tile + r * BK32 + p * 8);
}

__device__ __forceinline__ void stage_prologue32(
    const ushort_t* __restrict__ gA, const ushort_t* __restrict__ gB,
    ushort_t (&Abuf)[4][BT * BK32], ushort_t (&Bbuf)[4][BT * BK32], int wave, int lane) {
#pragma unroll
    for (int s = 0; s < 3; s++) {
        stage32(gA + s * BK32, Abuf[s], wave, lane);
        stage32(gB + s * BK32, Bbuf[s], wave, lane);
    }
}

// 4-buffer, 3-step-lookahead K-loop. Per step/wave: 4 stage loads, vmcnt(12),
// barrier, 12 ds_read_b128 + 32 MFMA (setprio-wrapped), barrier.
__device__ __forceinline__ void gemm_main32(
    const ushort_t* __restrict__ gA, const ushort_t* __restrict__ gB,
    ushort_t (&Abuf)[4][BT * BK32], ushort_t (&Bbuf)[4][BT * BK32],
    floatx4 (&acc)[8][4], int wave, int lane, int wr, int wc) {
#pragma unroll
    for (int t = 0; t < NSTEP2; t++) {
        if (t + 3 < NSTEP2) {
            stage32(gA + (t + 3) * BK32, Abuf[(t + 3) & 3], wave, lane);
            stage32(gB + (t + 3) * BK32, Bbuf[(t + 3) & 3], wave, lane);
        }
        if (t < 13)       asm volatile("s_waitcnt vmcnt(12)" ::: "memory");
        else if (t == 13) asm volatile("s_waitcnt vmcnt(8)"  ::: "memory");
        else if (t == 14) asm volatile("s_waitcnt vmcnt(4)"  ::: "memory");
        else              asm volatile("s_waitcnt vmcnt(0)"  ::: "memory");
        __builtin_amdgcn_sched_barrier(0);
        __builtin_amdgcn_s_barrier();
        short8 a[8], b[4];
#pragma unroll
        for (int m = 0; m < 8; m++) a[m] = read_frag32(Abuf[t & 3], wr * 8 + m, lane);
#pragma unroll
        for (int n = 0; n < 4; n++) b[n] = read_frag32(Bbuf[t & 3], wc * 4 + n, lane);
        __builtin_amdgcn_s_setprio(1);
#pragma unroll
        for (int m = 0; m < 8; m++)
#pragma unroll
            for (int n = 0; n < 4; n++)
                acc[m][n] = __builtin_amdgcn_mfma_f32_16x16x32_bf16(a[m], b[n], acc[m][n], 0, 0, 0);
        __builtin_amdgcn_s_setprio(0);
        __builtin_amdgcn_sched_barrier(0);
        __builtin_amdgcn_s_barrier();
    }
}

// ======== fused cooperative kernel ========
__global__ __launch_bounds__(512, 2) void fused_kernel(
    const float* __restrict__ img, const float* __restrict__ txt,
    const int* __restrict__ instr,
    ushort_t* __restrict__ Ibf, ushort_t* __restrict__ Tbf,
    float* __restrict__ inorm_r, float* __restrict__ tnorm_r,
    unsigned* __restrict__ mn_u, unsigned* __restrict__ mx_u,
    float* __restrict__ out) {
    __shared__ __align__(16) ushort_t Abuf[4][BT * BK32];   // 64 KB
    __shared__ __align__(16) ushort_t Bbuf[4][BT * BK32];   // 64 KB
    const int tile_j = blockIdx.x, tile_i = blockIdx.y;
    const int tid = threadIdx.x, wave = tid >> 6, lane = tid & 63;
    const int wr = wave >> 2, wc = wave & 3;
    cg::grid_group grid = cg::this_grid();

    // ---- P0: convert + reciprocal norms + init (16 rows per block) ----
    {
        const int b = tile_i * NTILE + tile_j;
#pragma unroll
        for (int r2 = 0; r2 < 2; r2++) {
            const int row = b * 16 + wave * 2 + r2;
            const int col0 = lane * 8;
            {
                const float4* p = reinterpret_cast<const float4*>(img + (size_t)row * DIM + col0);
                float4 a = p[0], bb = p[1];
                float ss = a.x*a.x + a.y*a.y + a.z*a.z + a.w*a.w
                         + bb.x*bb.x + bb.y*bb.y + bb.z*bb.z + bb.w*bb.w;
                ushort8 o;
                o[0]=f2bf(a.x); o[1]=f2bf(a.y); o[2]=f2bf(a.z); o[3]=f2bf(a.w);
                o[4]=f2bf(bb.x); o[5]=f2bf(bb.y); o[6]=f2bf(bb.z); o[7]=f2bf(bb.w);
                *reinterpret_cast<ushort8*>(Ibf + (size_t)row * DIM + col0) = o;
#pragma unroll
                for (int s = 1; s < 64; s <<= 1) ss += __shfl_xor(ss, s);
                if (lane == 0) inorm_r[row] = 1.0f / sqrtf(ss);
            }
            {
                const float4* p = reinterpret_cast<const float4*>(txt + (size_t)row * DIM + col0);
                float4 a = p[0], bb = p[1];
                float ss = a.x*a.x + a.y*a.y + a.z*a.z + a.w*a.w
                         + bb.x*bb.x + bb.y*bb.y + bb.z*bb.z + bb.w*bb.w;
                ushort8 o;
                o[0]=f2bf(a.x); o[1]=f2bf(a.y); o[2]=f2bf(a.z); o[3]=f2bf(a.w);
                o[4]=f2bf(bb.x); o[5]=f2bf(bb.y); o[6]=f2bf(bb.z); o[7]=f2bf(bb.w);
                *reinterpret_cast<ushort8*>(Tbf + (size_t)row * DIM + col0) = o;
#pragma unroll
                for (int s = 1; s < 64; s <<= 1) ss += __shfl_xor(ss, s);
                if (lane == 0) tnorm_r[row] = 1.0f / sqrtf(ss);
            }
        }
        if (tid < 16) {
            int row = b * 16 + tid;
            mn_u[row] = 0xFFFFFFFFu; mx_u[row] = 0u;
        }
        if (b == 0 && tid == 0) out[0] = 0.0f;
    }
    __threadfence();
    grid.sync();
    __threadfence();

    const ushort_t* gTi = Tbf + (size_t)(tile_i * BT) * DIM;
    const ushort_t* gTj = Tbf + (size_t)(tile_j * BT) * DIM;
    const ushort_t* gIi = Ibf + (size_t)(tile_i * BT) * DIM;

    floatx4 acc[8][4];
#pragma unroll
    for (int m = 0; m < 8; m++)
#pragma unroll
        for (int n = 0; n < 4; n++) acc[m][n] = (floatx4){0.f, 0.f, 0.f, 0.f};

    // ---- P1a: S = T_i . T_j^T ----
    stage_prologue32(gTi, gTj, Abuf, Bbuf, wave, lane);
    gemm_main32(gTi, gTj, Abuf, Bbuf, acc, wave, lane, wr, wc);

    // issue D prologue stages early (pull hides under minmax/pack VALU)
    stage_prologue32(gIi, gTj, Abuf, Bbuf, wave, lane);

    // per-row min/max (fp32-exact) + device atomics
#pragma unroll
    for (int m = 0; m < 8; m++) {
#pragma unroll
        for (int reg = 0; reg < 4; reg++) {
            float vmin = acc[m][0][reg], vmax = acc[m][0][reg];
#pragma unroll
            for (int n = 1; n < 4; n++) {
                vmin = fminf(vmin, acc[m][n][reg]);
                vmax = fmaxf(vmax, acc[m][n][reg]);
            }
#pragma unroll
            for (int s = 1; s < 16; s <<= 1) {
                vmin = fminf(vmin, __shfl_xor(vmin, s));
                vmax = fmaxf(vmax, __shfl_xor(vmax, s));
            }
            if ((lane & 15) == 0) {
                int row_g = tile_i * BT + wr * 128 + m * 16 + (lane >> 4) * 4 + reg;
                atomicMin(&mn_u[row_g], fmap(vmin));
                atomicMax(&mx_u[row_g], fmap(vmax));
            }
        }
    }

    // pack sim to bf16 IN REGISTERS (64 VGPR), free acc for D
    ushort8 sim[16];
#pragma unroll
    for (int c = 0; c < 16; c++) {
        int m = c >> 1, n0 = (c & 1) * 2;
        ushort8 o;
        o[0] = f2bf(acc[m][n0][0]);     o[1] = f2bf(acc[m][n0][1]);
        o[2] = f2bf(acc[m][n0][2]);     o[3] = f2bf(acc[m][n0][3]);
        o[4] = f2bf(acc[m][n0 + 1][0]); o[5] = f2bf(acc[m][n0 + 1][1]);
        o[6] = f2bf(acc[m][n0 + 1][2]); o[7] = f2bf(acc[m][n0 + 1][3]);
        sim[c] = o;
    }

    // ---- P1b: D = I_i . T_j^T ----
#pragma unroll
    for (int m = 0; m < 8; m++)
#pragma unroll
        for (int n = 0; n < 4; n++) acc[m][n] = (floatx4){0.f, 0.f, 0.f, 0.f};
    gemm_main32(gIi, gTj, Abuf, Bbuf, acc, wave, lane, wr, wc);

    __threadfence();
    grid.sync();
    __threadfence();

    // ---- P2: loss epilogue (everything in regs / L2-hot scalars) ----
    const int rbase0 = tile_i * BT + wr * 128;
    const int cbase0 = tile_j * BT + wc * 64;
    float rtn4[4]; int ic4[4];
#pragma unroll
    for (int n = 0; n < 4; n++) {
        int col_g = cbase0 + n * 16 + (lane & 15);
        rtn4[n] = tnorm_r[col_g];
        ic4[n] = instr[col_g];
    }
    float lsum = 0.f;
#pragma unroll
    for (int m = 0; m < 8; m++) {
        ushort8 s0 = sim[m * 2 + 0];
        ushort8 s1 = sim[m * 2 + 1];
        int rb = rbase0 + m * 16 + (lane >> 4) * 4;
#pragma unroll
        for (int reg = 0; reg < 4; reg++) {
            int row_g = rb + reg;
            float rinr = inorm_r[row_g];
            float mnv = funmap(mn_u[row_g]);
            float mxv = funmap(mx_u[row_g]);
            float winv = 1.0f / (mxv - mnv + EPS_W);
            int   ir  = instr[row_g];
#pragma unroll
            for (int n = 0; n < 4; n++) {
                int col_g = cbase0 + n * 16 + (lane & 15);
                float simv = (n < 2) ? bf2f(s0[(n & 1) * 4 + reg])
                                     : bf2f(s1[(n & 1) * 4 + reg]);
                float cosv = acc[m][n][reg] * (rinr * rtn4[n]);
                float w = (simv - mnv) * winv;
                bool aligned = (ir == ic4[n]) || (row_g == col_g);
                lsum += aligned ? (1.0f - cosv) : fmaxf(0.0f, cosv - w);
            }
        }
    }
#pragma unroll
    for (int s = 1; s < 64; s <<= 1) lsum += __shfl_xor(lsum, s);
    if (lane == 0)
        atomicAdd(out, lsum * (1.0f / ((float)NROWS * (float)NROWS)));
}

// ======== fallback path (round-4 kernels, BK=64) ========
__device__ inline void stage_tile(const ushort_t* __restrict__ gbase,
                                  ushort_t* lds, int wave, int lane) {
#pragma unroll
    for (int q = 0; q < 4; q++) {
        int row0 = wave * 32 + q * 8;
        int lrow = row0 + (lane >> 3);
        int src_chunk = (lane & 7) ^ (lane >> 3);
        const ushort_t* g = gbase + (size_t)lrow * DIM + src_chunk * 8;
        gload_lds16(g, lds + row0 * 64);
    }
}
__device__ inline short8 read_frag(const ushort_t* tile, int frag_row, int kk, int lane) {
    int r = frag_row * 16 + (lane & 15);
    int c = (kk * 4 + (lane >> 4)) ^ (lane & 7);
    return *reinterpret_cast<const short8*>(tile + r * 64 + c * 8);
}

__global__ __launch_bounds__(256) void prep_kernel(
    const float* __restrict__ img, const float* __restrict__ txt,
    ushort_t* __restrict__ Ibf, ushort_t* __restrict__ Tbf,
    float* __restrict__ img_norm, float* __restrict__ txt_norm,
    unsigned* __restrict__ mn_u, unsigned* __restrict__ mx_u) {
    const int wave = threadIdx.x >> 6, lane = threadIdx.x & 63;
    const int row = blockIdx.x * 4 + wave;
    const int col0 = lane * 8;
    {
        const float4* p = reinterpret_cast<const float4*>(img + (size_t)row * DIM + col0);
        float4 a = p[0], b = p[1];
        float ss = a.x*a.x + a.y*a.y + a.z*a.z + a.w*a.w
                 + b.x*b.x + b.y*b.y + b.z*b.z + b.w*b.w;
        ushort8 o;
        o[0]=f2bf(a.x); o[1]=f2bf(a.y); o[2]=f2bf(a.z); o[3]=f2bf(a.w);
        o[4]=f2bf(b.x); o[5]=f2bf(b.y); o[6]=f2bf(b.z); o[7]=f2bf(b.w);
        *reinterpret_cast<ushort8*>(Ibf + (size_t)row * DIM + col0) = o;
#pragma unroll
        for (int s = 1; s < 64; s <<= 1) ss += __shfl_xor(ss, s);
        if (lane == 0) img_norm[row] = sqrtf(ss);
    }
    {
        const float4* p = reinterpret_cast<const float4*>(txt + (size_t)row * DIM + col0);
        float4 a = p[0], b = p[1];
        float ss = a.x*a.x + a.y*a.y + a.z*a.z + a.w*a.w
                 + b.x*b.x + b.y*b.y + b.z*b.z + b.w*b.w;
        ushort8 o;
        o[0]=f2bf(a.x); o[1]=f2bf(a.y); o[2]=f2bf(a.z); o[3]=f2bf(a.w);
        o[4]=f2bf(b.x); o[5]=f2bf(b.y); o[6]=f2bf(b.z); o[7]=f2bf(b.w);
        *reinterpret_cast<ushort8*>(Tbf + (size_t)row * DIM + col0) = o;
#pragma unroll
        for (int s = 1; s < 64; s <<= 1) ss += __shfl_xor(ss, s);
        if (lane == 0) txt_norm[row] = sqrtf(ss);
    }
    if (lane == 0) { mn_u[row] = 0xFFFFFFFFu; mx_u[row] = 0u; }
}

__global__ __launch_bounds__(512, 2) void phase1_kernel(
    const ushort_t* __restrict__ Tbf,
    unsigned* __restrict__ mn_u, unsigned* __restrict__ mx_u,
    ushort_t* __restrict__ simbuf) {
    __shared__ __align__(16) ushort_t Ta[2][BT * 64];
    __shared__ __align__(16) ushort_t Tb[2][BT * 64];
    const int tile_j = blockIdx.x, tile_i = blockIdx.y;
    const int tid = threadIdx.x;
    const int wave = tid >> 6, lane = tid & 63;
    const int wr = wave >> 2, wc = wave & 3;
    const ushort_t* gA = Tbf + (size_t)(tile_i * BT) * DIM;
    const ushort_t* gB = Tbf + (size_t)(tile_j * BT) * DIM;

    floatx4 acc[8][4];
#pragma unroll
    for (int m = 0; m < 8; m++)
#pragma unroll
        for (int n = 0; n < 4; n++) acc[m][n] = (floatx4){0.f, 0.f, 0.f, 0.f};

    stage_tile(gA, Ta[0], wave, lane);
    stage_tile(gB, Tb[0], wave, lane);
    __syncthreads();
    int cur = 0;
    for (int t = 0; t < NKSTEP; t++) {
        if (t + 1 < NKSTEP) {
            stage_tile(gA + (t + 1) * 64, Ta[cur ^ 1], wave, lane);
            stage_tile(gB + (t + 1) * 64, Tb[cur ^ 1], wave, lane);
        }
#pragma unroll
        for (int kk = 0; kk < 2; kk++) {
            short8 a[8], b[4];
#pragma unroll
            for (int m = 0; m < 8; m++) a[m] = read_frag(Ta[cur], wr * 8 + m, kk, lane);
#pragma unroll
            for (int n = 0; n < 4; n++) b[n] = read_frag(Tb[cur], wc * 4 + n, kk, lane);
#pragma unroll
            for (int m = 0; m < 8; m++)
#pragma unroll
                for (int n = 0; n < 4; n++)
                    acc[m][n] = __builtin_amdgcn_mfma_f32_16x16x32_bf16(a[m], b[n], acc[m][n], 0, 0, 0);
        }
        __syncthreads();
        cur ^= 1;
    }
#pragma unroll
    for (int m = 0; m < 8; m++) {
#pragma unroll
        for (int reg = 0; reg < 4; reg++) {
            float vmin = acc[m][0][reg], vmax = acc[m][0][reg];
#pragma unroll
            for (int n = 1; n < 4; n++) {
                vmin = fminf(vmin, acc[m][n][reg]);
                vmax = fmaxf(vmax, acc[m][n][reg]);
            }
#pragma unroll
            for (int s = 1; s < 16; s <<= 1) {
                vmin = fminf(vmin, __shfl_xor(vmin, s));
                vmax = fmaxf(vmax, __shfl_xor(vmax, s));
            }
            if ((lane & 15) == 0) {
                int row_g = tile_i * BT + wr * 128 + m * 16 + (lane >> 4) * 4 + reg;
                atomicMin(&mn_u[row_g], fmap(vmin));
                atomicMax(&mx_u[row_g], fmap(vmax));
            }
        }
    }
    ushort_t* sp = simbuf + (((size_t)(tile_i * NTILE + tile_j) * 512 + tid) * 128);
#pragma unroll
    for (int c = 0; c < 16; c++) {
        int m = c >> 1, n0 = (c & 1) * 2;
        ushort8 o;
        o[0] = f2bf(acc[m][n0][0]);     o[1] = f2bf(acc[m][n0][1]);
        o[2] = f2bf(acc[m][n0][2]);     o[3] = f2bf(acc[m][n0][3]);
        o[4] = f2bf(acc[m][n0 + 1][0]); o[5] = f2bf(acc[m][n0 + 1][1]);
        o[6] = f2bf(acc[m][n0 + 1][2]); o[7] = f2bf(acc[m][n0 + 1][3]);
        reinterpret_cast<ushort8*>(sp)[c] = o;
    }
}

__global__ __launch_bounds__(256) void params_kernel(
    const float* __restrict__ img_norm, const float* __restrict__ txt_norm,
    const unsigned* __restrict__ mn_u, const unsigned* __restrict__ mx_u,
    float4* __restrict__ params) {
    int i = blockIdx.x * 256 + threadIdx.x;
    float mn = funmap(mn_u[i]), mx = funmap(mx_u[i]);
    params[i] = make_float4(1.0f / img_norm[i], 1.0f / txt_norm[i],
                            mn, 1.0f / (mx - mn + EPS_W));
}

__global__ __launch_bounds__(512, 2) void phase2_kernel(
    const ushort_t* __restrict__ Ibf, const ushort_t* __restrict__ Tbf,
    const float4* __restrict__ params, const int* __restrict__ instr,
    const ushort_t* __restrict__ simbuf, float* __restrict__ out) {
    __shared__ __align__(16) ushort_t Ta[2][BT * 64];
    __shared__ __align__(16) ushort_t Tb[2][BT * 64];
    const int tile_j = blockIdx.x, tile_i = blockIdx.y;
    const int tid = threadIdx.x;
    const int wave = tid >> 6, lane = tid & 63;
    const int wr = wave >> 2, wc = wave & 3;
    const ushort_t* gA = Ibf + (size_t)(tile_i * BT) * DIM;
    const ushort_t* gB = Tbf + (size_t)(tile_j * BT) * DIM;

    ushort8 sim[16];
    {
        const ushort8* spv = reinterpret_cast<const ushort8*>(
            simbuf + (((size_t)(tile_i * NTILE + tile_j) * 512 + tid) * 128));
#pragma unroll
        for (int c = 0; c < 16; c++) sim[c] = spv[c];
    }

    floatx4 acc[8][4];
#pragma unroll
    for (int m = 0; m < 8; m++)
#pragma unroll
        for (int n = 0; n < 4; n++) acc[m][n] = (floatx4){0.f, 0.f, 0.f, 0.f};

    stage_tile(gA, Ta[0], wave, lane);
    stage_tile(gB, Tb[0], wave, lane);
    __syncthreads();
    int cur = 0;
    for (int t = 0; t < NKSTEP; t++) {
        if (t + 1 < NKSTEP) {
            stage_tile(gA + (t + 1) * 64, Ta[cur ^ 1], wave, lane);
            stage_tile(gB + (t + 1) * 64, Tb[cur ^ 1], wave, lane);
        }
#pragma unroll
        for (int kk = 0; kk < 2; kk++) {
            short8 a[8], b[4];
#pragma unroll
            for (int m = 0; m < 8; m++) a[m] = read_frag(Ta[cur], wr * 8 + m, kk, lane);
#pragma unroll
            for (int n = 0; n < 4; n++) b[n] = read_frag(Tb[cur], wc * 4 + n, kk, lane);
#pragma unroll
            for (int m = 0; m < 8; m++)
#pragma unroll
                for (int n = 0; n < 4; n++)
                    acc[m][n] = __builtin_amdgcn_mfma_f32_16x16x32_bf16(a[m], b[n], acc[m][n], 0, 0, 0);
        }
        __syncthreads();
        cur ^= 1;
    }

    const int rbase0 = tile_i * BT + wr * 128;
    const int cbase0 = tile_j * BT + wc * 64;
    float rtn4[4]; int ic4[4];
#pragma unroll
    for (int n = 0; n < 4; n++) {
        int col_g = cbase0 + n * 16 + (lane & 15);
        rtn4[n] = params[col_g].y;
        ic4[n] = instr[col_g];
    }
    float lsum = 0.f;
#pragma unroll
    for (int m = 0; m < 8; m++) {
        ushort8 s0 = sim[m * 2 + 0];
        ushort8 s1 = sim[m * 2 + 1];
        int rb = rbase0 + m * 16 + (lane >> 4) * 4;
#pragma unroll
        for (int reg = 0; reg < 4; reg++) {
            int row_g = rb + reg;
            float4 pp = params[row_g];
            int   ir  = instr[row_g];
#pragma unroll
            for (int n = 0; n < 4; n++) {
                int col_g = cbase0 + n * 16 + (lane & 15);
                float simv = (n < 2) ? bf2f(s0[(n & 1) * 4 + reg])
                                     : bf2f(s1[(n & 1) * 4 + reg]);
                float cosv = acc[m][n][reg] * (pp.x * rtn4[n]);
                float w = (simv - pp.z) * pp.w;
                bool aligned = (ir == ic4[n]) || (row_g == col_g);
                lsum += aligned ? (1.0f - cosv) : fmaxf(0.0f, cosv - w);
            }
        }
    }
#pragma unroll
    for (int s = 1; s < 64; s <<= 1) lsum += __shfl_xor(lsum, s);
    if (lane == 0)
        atomicAdd(out, lsum * (1.0f / ((float)NROWS * (float)NROWS)));
}

// ---------- launch ----------
extern "C" void kernel_launch(void* const* d_in, const int* in_sizes, int n_in,
                              void* d_out, int out_size, void* d_ws, size_t ws_size,
                              hipStream_t stream) {
    const float* img = (const float*)d_in[0];
    const float* txt = (const float*)d_in[1];
    const int* instr = (const int*)d_in[2];
    float* out = (float*)d_out;

    char* ws = (char*)d_ws;
    ushort_t* Tbf = (ushort_t*)ws;                                  // 4 MB
    ushort_t* Ibf = (ushort_t*)(ws + (size_t)NROWS * DIM * 2);      // 4 MB
    float* inorm = (float*)(ws + (size_t)NROWS * DIM * 4);          // 16 KB
    float* tnorm = inorm + NROWS;                                   // 16 KB
    unsigned* mn_u = (unsigned*)(tnorm + NROWS);                    // 16 KB
    unsigned* mx_u = mn_u + NROWS;                                  // 16 KB
    float4* params = (float4*)(mx_u + NROWS);                       // 64 KB (fallback)
    ushort_t* simbuf = (ushort_t*)(params + NROWS);                 // 32 MB (fallback)

    void* kargs[] = { (void*)&img, (void*)&txt, (void*)&instr,
                      (void*)&Ibf, (void*)&Tbf, (void*)&inorm, (void*)&tnorm,
                      (void*)&mn_u, (void*)&mx_u, (void*)&out };
    hipError_t err = hipLaunchCooperativeKernel((const void*)fused_kernel,
                                                dim3(NTILE, NTILE), dim3(512),
                                                kargs, 0, stream);
    if (err != hipSuccess) {
        // fallback: round-4 4-kernel path
        hipMemsetAsync(d_out, 0, sizeof(float), stream);
        prep_kernel<<<NROWS / 4, 256, 0, stream>>>(img, txt, Ibf, Tbf,
                                                   inorm, tnorm, mn_u, mx_u);
        dim3 grid(NTILE, NTILE);
        phase1_kernel<<<grid, 512, 0, stream>>>(Tbf, mn_u, mx_u, simbuf);
        params_kernel<<<NROWS / 256, 256, 0, stream>>>(inorm, tnorm, mn_u, mx_u, params);
        phase2_kernel<<<grid, 512, 0, stream>>>(Ibf, Tbf, params, instr, simbuf, out);
    }
}

// Round 6
// 123.997 us; speedup vs baseline: 2.9944x; 2.9944x over previous
//
#include <hip/hip_runtime.h>
#include <stdint.h>

#define NROWS 4096
#define DIM   512
#define EPS_COS 1e-8f
#define EPS_W   1e-6f
#define BM    128                  // tile rows (M)
#define BN    256                  // tile cols (N)
#define BK32  32
#define NTI   (NROWS / BM)         // 32 i-tiles
#define NTJ   (NROWS / BN)         // 16 j-tiles
#define NSTEP (DIM / BK32)         // 16 K-steps

typedef unsigned short ushort_t;
typedef __attribute__((ext_vector_type(8))) short   short8;
typedef __attribute__((ext_vector_type(8))) unsigned short ushort8;
typedef __attribute__((ext_vector_type(4))) float   floatx4;

// ---------- helpers ----------
__device__ inline ushort_t f2bf(float x) {            // RNE float->bf16
    unsigned u = __float_as_uint(x);
    unsigned r = (u + 0x7FFFu + ((u >> 16) & 1u)) >> 16;
    return (ushort_t)r;
}
__device__ inline float bf2f(ushort_t u) {
    return __uint_as_float(((unsigned)u) << 16);
}
// monotone float<->uint mapping for atomicMin/Max on floats
__device__ inline unsigned fmap(float f) {
    unsigned u = __float_as_uint(f);
    return (u & 0x80000000u) ? ~u : (u | 0x80000000u);
}
__device__ inline float funmap(unsigned u) {
    return __uint_as_float((u & 0x80000000u) ? (u & 0x7fffffffu) : ~u);
}

__device__ inline void gload_lds16(const void* g, void* l) {
    auto* gp = reinterpret_cast<const __attribute__((address_space(1))) unsigned int*>(
        reinterpret_cast<uintptr_t>(g));
    auto* lp = reinterpret_cast<__attribute__((address_space(3))) unsigned int*>(
        reinterpret_cast<uintptr_t>(l));
    __builtin_amdgcn_global_load_lds(gp, lp, 16, 0, 0);
}

// ======== BK=32 staging (verified correct in round 5) ========
// [rows][32] bf16 tile, 64 B rows = 4 chunks of 16 B.
// LDS[r][p] holds logical chunk p ^ ((r>>1)&3): start banks over 8 rows
// {0,16,4,20,8,24,12,28} -> conflict-free minimum for wave64 b128 reads.

// A-tile: 128 rows, 512 threads -> 1 chunk each.
__device__ __forceinline__ void stageA32(const ushort_t* __restrict__ gbase,
                                         ushort_t* lds, int tid) {
    int lrow = tid >> 2;
    int gchunk = (tid & 3) ^ ((lrow >> 1) & 3);
    int wave = tid >> 6;
    gload_lds16(gbase + (size_t)lrow * DIM + gchunk * 8, lds + (wave * 16) * BK32);
}
// B-tile: 256 rows, 2 chunks per thread.
__device__ __forceinline__ void stageB32(const ushort_t* __restrict__ gbase,
                                         ushort_t* lds, int wave, int lane) {
#pragma unroll
    for (int q = 0; q < 2; q++) {
        int row0 = wave * 32 + q * 16;
        int lrow = row0 + (lane >> 2);
        int gchunk = (lane & 3) ^ ((lrow >> 1) & 3);
        gload_lds16(gbase + (size_t)lrow * DIM + gchunk * 8, lds + row0 * BK32);
    }
}
// fragment read (verified round 5): lane l -> row fr*16+(l&15), chunk (l>>4)^((r>>1)&3)
__device__ __forceinline__ short8 read_frag32(const ushort_t* tile, int fr, int lane) {
    int r = fr * 16 + (lane & 15);
    int p = (lane >> 4) ^ ((r >> 1) & 3);
    return *reinterpret_cast<const short8*>(tile + r * BK32 + p * 8);
}

// XCD region swizzle: xcd = bid&7 (HW round-robin), each XCD gets an
// 8x8 tile region -> working set 1 MB (A) + 2 MB (B) < 4 MB per-XCD L2.
__device__ __forceinline__ void tile_map(int bid, int& tile_i, int& tile_j) {
    int xcd = bid & 7, within = bid >> 3;           // within 0..63
    tile_i = (xcd >> 1) * 8 + (within >> 3);        // 0..31
    tile_j = (xcd & 1) * 8 + (within & 7);          // 0..15
}

// ---------- kernel 1: convert + norms + init ----------
__global__ __launch_bounds__(256) void prep_kernel(
    const float* __restrict__ img, const float* __restrict__ txt,
    ushort_t* __restrict__ Ibf, ushort_t* __restrict__ Tbf,
    float* __restrict__ img_norm, float* __restrict__ txt_norm,
    unsigned* __restrict__ mn_u, unsigned* __restrict__ mx_u) {
    const int wave = threadIdx.x >> 6, lane = threadIdx.x & 63;
    const int row = blockIdx.x * 4 + wave;
    const int col0 = lane * 8;
    {
        const float4* p = reinterpret_cast<const float4*>(img + (size_t)row * DIM + col0);
        float4 a = p[0], b = p[1];
        float ss = a.x*a.x + a.y*a.y + a.z*a.z + a.w*a.w
                 + b.x*b.x + b.y*b.y + b.z*b.z + b.w*b.w;
        ushort8 o;
        o[0]=f2bf(a.x); o[1]=f2bf(a.y); o[2]=f2bf(a.z); o[3]=f2bf(a.w);
        o[4]=f2bf(b.x); o[5]=f2bf(b.y); o[6]=f2bf(b.z); o[7]=f2bf(b.w);
        *reinterpret_cast<ushort8*>(Ibf + (size_t)row * DIM + col0) = o;
#pragma unroll
        for (int s = 1; s < 64; s <<= 1) ss += __shfl_xor(ss, s);
        if (lane == 0) img_norm[row] = sqrtf(ss);
    }
    {
        const float4* p = reinterpret_cast<const float4*>(txt + (size_t)row * DIM + col0);
        float4 a = p[0], b = p[1];
        float ss = a.x*a.x + a.y*a.y + a.z*a.z + a.w*a.w
                 + b.x*b.x + b.y*b.y + b.z*b.z + b.w*b.w;
        ushort8 o;
        o[0]=f2bf(a.x); o[1]=f2bf(a.y); o[2]=f2bf(a.z); o[3]=f2bf(a.w);
        o[4]=f2bf(b.x); o[5]=f2bf(b.y); o[6]=f2bf(b.z); o[7]=f2bf(b.w);
        *reinterpret_cast<ushort8*>(Tbf + (size_t)row * DIM + col0) = o;
#pragma unroll
        for (int s = 1; s < 64; s <<= 1) ss += __shfl_xor(ss, s);
        if (lane == 0) txt_norm[row] = sqrtf(ss);
    }
    if (lane == 0) { mn_u[row] = 0xFFFFFFFFu; mx_u[row] = 0u; }
}

// ---- shared K-loop: 3 buffers, 2-deep lookahead, counted vmcnt ----
// Per thread per step: 3 loads (A:1, B:2). Outstanding at wait = 6 (t+1,t+2).
#define GEMM_LOOP(gA, gB)                                                      \
    stageA32(gA, Abuf[0], tid); stageB32(gB, Bbuf[0], wave, lane);             \
    stageA32(gA + BK32, Abuf[1], tid); stageB32(gB + BK32, Bbuf[1], wave, lane);\
    _Pragma("unroll")                                                          \
    for (int t = 0; t < NSTEP; t++) {                                          \
        if (t + 2 < NSTEP) {                                                   \
            stageA32(gA + (t + 2) * BK32, Abuf[(t + 2) % 3], tid);             \
            stageB32(gB + (t + 2) * BK32, Bbuf[(t + 2) % 3], wave, lane);      \
        }                                                                      \
        if (t < NSTEP - 2)      asm volatile("s_waitcnt vmcnt(6)" ::: "memory");\
        else if (t == NSTEP - 2) asm volatile("s_waitcnt vmcnt(3)" ::: "memory");\
        else                    asm volatile("s_waitcnt vmcnt(0)" ::: "memory");\
        __builtin_amdgcn_sched_barrier(0);                                     \
        __builtin_amdgcn_s_barrier();                                          \
        short8 afr[4], bfr[4];                                                 \
        _Pragma("unroll")                                                      \
        for (int m = 0; m < 4; m++) afr[m] = read_frag32(Abuf[t % 3], wr * 4 + m, lane);\
        _Pragma("unroll")                                                      \
        for (int n = 0; n < 4; n++) bfr[n] = read_frag32(Bbuf[t % 3], wc * 4 + n, lane);\
        __builtin_amdgcn_s_setprio(1);                                         \
        _Pragma("unroll")                                                      \
        for (int m = 0; m < 4; m++)                                            \
            _Pragma("unroll")                                                  \
            for (int n = 0; n < 4; n++)                                        \
                acc[m][n] = __builtin_amdgcn_mfma_f32_16x16x32_bf16(afr[m], bfr[n], acc[m][n], 0, 0, 0);\
        __builtin_amdgcn_s_setprio(0);                                         \
        __builtin_amdgcn_sched_barrier(0);                                     \
        __builtin_amdgcn_s_barrier();                                          \
    }

// ---------- kernel 2: S = T.T^T -> minmax atomics + packed bf16 sim ----------
__global__ __launch_bounds__(512, 4) void phase1_kernel(
    const ushort_t* __restrict__ Tbf,
    unsigned* __restrict__ mn_u, unsigned* __restrict__ mx_u,
    ushort_t* __restrict__ simbuf) {
    __shared__ __align__(16) ushort_t Abuf[3][BM * BK32];   // 24 KB
    __shared__ __align__(16) ushort_t Bbuf[3][BN * BK32];   // 48 KB
    int tile_i, tile_j;
    tile_map(blockIdx.x, tile_i, tile_j);
    const int tid = threadIdx.x, wave = tid >> 6, lane = tid & 63;
    const int wr = wave >> 2, wc = wave & 3;    // 2x4 waves; 64x64 per wave
    const ushort_t* gA = Tbf + (size_t)(tile_i * BM) * DIM;
    const ushort_t* gB = Tbf + (size_t)(tile_j * BN) * DIM;

    floatx4 acc[4][4];
#pragma unroll
    for (int m = 0; m < 4; m++)
#pragma unroll
        for (int n = 0; n < 4; n++) acc[m][n] = (floatx4){0.f, 0.f, 0.f, 0.f};

    GEMM_LOOP(gA, gB)

    // per-row min/max (fp32-exact)
#pragma unroll
    for (int m = 0; m < 4; m++) {
#pragma unroll
        for (int reg = 0; reg < 4; reg++) {
            float vmin = acc[m][0][reg], vmax = acc[m][0][reg];
#pragma unroll
            for (int n = 1; n < 4; n++) {
                vmin = fminf(vmin, acc[m][n][reg]);
                vmax = fmaxf(vmax, acc[m][n][reg]);
            }
#pragma unroll
            for (int s = 1; s < 16; s <<= 1) {
                vmin = fminf(vmin, __shfl_xor(vmin, s));
                vmax = fmaxf(vmax, __shfl_xor(vmax, s));
            }
            if ((lane & 15) == 0) {
                int row_g = tile_i * BM + wr * 64 + m * 16 + (lane >> 4) * 4 + reg;
                atomicMin(&mn_u[row_g], fmap(vmin));
                atomicMax(&mx_u[row_g], fmap(vmax));
            }
        }
    }

    // packed bf16 store (8 x 16B per lane, coalesced); idx = m*16 + n*4 + reg
    ushort_t* sp = simbuf + (((size_t)(tile_i * NTJ + tile_j) * 512 + tid) * 64);
#pragma unroll
    for (int c = 0; c < 8; c++) {
        int m = c >> 1, n0 = (c & 1) * 2;
        ushort8 o;
        o[0] = f2bf(acc[m][n0][0]);     o[1] = f2bf(acc[m][n0][1]);
        o[2] = f2bf(acc[m][n0][2]);     o[3] = f2bf(acc[m][n0][3]);
        o[4] = f2bf(acc[m][n0 + 1][0]); o[5] = f2bf(acc[m][n0 + 1][1]);
        o[6] = f2bf(acc[m][n0 + 1][2]); o[7] = f2bf(acc[m][n0 + 1][3]);
        reinterpret_cast<ushort8*>(sp)[c] = o;
    }
}

// ---------- kernel 2.5: per-row params {1/inorm, 1/tnorm, mn, 1/(mx-mn+eps)} ----------
__global__ __launch_bounds__(256) void params_kernel(
    const float* __restrict__ img_norm, const float* __restrict__ txt_norm,
    const unsigned* __restrict__ mn_u, const unsigned* __restrict__ mx_u,
    float4* __restrict__ params) {
    int i = blockIdx.x * 256 + threadIdx.x;
    float mn = funmap(mn_u[i]), mx = funmap(mx_u[i]);
    params[i] = make_float4(1.0f / img_norm[i], 1.0f / txt_norm[i],
                            mn, 1.0f / (mx - mn + EPS_W));
}

// ---------- kernel 3: D = I.T^T + loss epilogue ----------
__global__ __launch_bounds__(512, 4) void phase2_kernel(
    const ushort_t* __restrict__ Ibf, const ushort_t* __restrict__ Tbf,
    const float4* __restrict__ params, const int* __restrict__ instr,
    const ushort_t* __restrict__ simbuf, float* __restrict__ out) {
    __shared__ __align__(16) ushort_t Abuf[3][BM * BK32];
    __shared__ __align__(16) ushort_t Bbuf[3][BN * BK32];
    int tile_i, tile_j;
    tile_map(blockIdx.x, tile_i, tile_j);
    const int tid = threadIdx.x, wave = tid >> 6, lane = tid & 63;
    const int wr = wave >> 2, wc = wave & 3;
    const ushort_t* gA = Ibf + (size_t)(tile_i * BM) * DIM;
    const ushort_t* gB = Tbf + (size_t)(tile_j * BN) * DIM;

    floatx4 acc[4][4];
#pragma unroll
    for (int m = 0; m < 4; m++)
#pragma unroll
        for (int n = 0; n < 4; n++) acc[m][n] = (floatx4){0.f, 0.f, 0.f, 0.f};

    GEMM_LOOP(gA, gB)

    // epilogue: per-pair loss; sim read back in packed per-lane layout
    const int rbase0 = tile_i * BM + wr * 64;
    const int cbase0 = tile_j * BN + wc * 64;
    const ushort8* spv = reinterpret_cast<const ushort8*>(
        simbuf + (((size_t)(tile_i * NTJ + tile_j) * 512 + tid) * 64));
    float rtn4[4]; int ic4[4];
#pragma unroll
    for (int n = 0; n < 4; n++) {
        int col_g = cbase0 + n * 16 + (lane & 15);
        rtn4[n] = params[col_g].y;
        ic4[n] = instr[col_g];
    }
    float lsum = 0.f;
#pragma unroll
    for (int m = 0; m < 4; m++) {
        ushort8 s0 = spv[m * 2 + 0];
        ushort8 s1 = spv[m * 2 + 1];
        int rb = rbase0 + m * 16 + (lane >> 4) * 4;
#pragma unroll
        for (int reg = 0; reg < 4; reg++) {
            int row_g = rb + reg;
            float4 pp = params[row_g];        // {rinr, rtn, mn, winv}
            int   ir  = instr[row_g];
#pragma unroll
            for (int n = 0; n < 4; n++) {
                int col_g = cbase0 + n * 16 + (lane & 15);
                float simv = (n < 2) ? bf2f(s0[(n & 1) * 4 + reg])
                                     : bf2f(s1[(n & 1) * 4 + reg]);
                float cosv = acc[m][n][reg] * (pp.x * rtn4[n]);
                float w = (simv - pp.z) * pp.w;
                bool aligned = (ir == ic4[n]) || (row_g == col_g);
                lsum += aligned ? (1.0f - cosv) : fmaxf(0.0f, cosv - w);
            }
        }
    }
#pragma unroll
    for (int s = 1; s < 64; s <<= 1) lsum += __shfl_xor(lsum, s);
    if (lane == 0)
        atomicAdd(out, lsum * (1.0f / ((float)NROWS * (float)NROWS)));
}

// ---------- launch ----------
extern "C" void kernel_launch(void* const* d_in, const int* in_sizes, int n_in,
                              void* d_out, int out_size, void* d_ws, size_t ws_size,
                              hipStream_t stream) {
    const float* img = (const float*)d_in[0];
    const float* txt = (const float*)d_in[1];
    const int* instr = (const int*)d_in[2];
    float* out = (float*)d_out;

    char* ws = (char*)d_ws;
    ushort_t* Tbf = (ushort_t*)ws;                                  // 4 MB
    ushort_t* Ibf = (ushort_t*)(ws + (size_t)NROWS * DIM * 2);      // 4 MB
    float* inorm = (float*)(ws + (size_t)NROWS * DIM * 4);          // 16 KB
    float* tnorm = inorm + NROWS;                                   // 16 KB
    unsigned* mn_u = (unsigned*)(tnorm + NROWS);                    // 16 KB
    unsigned* mx_u = mn_u + NROWS;                                  // 16 KB
    float4* params = (float4*)(mx_u + NROWS);                       // 64 KB
    ushort_t* simbuf = (ushort_t*)(params + NROWS);                 // 32 MB

    hipMemsetAsync(d_out, 0, sizeof(float), stream);
    prep_kernel<<<NROWS / 4, 256, 0, stream>>>(img, txt, Ibf, Tbf,
                                               inorm, tnorm, mn_u, mx_u);
    phase1_kernel<<<NTI * NTJ, 512, 0, stream>>>(Tbf, mn_u, mx_u, simbuf);
    params_kernel<<<NROWS / 256, 256, 0, stream>>>(inorm, tnorm, mn_u, mx_u, params);
    phase2_kernel<<<NTI * NTJ, 512, 0, stream>>>(Ibf, Tbf, params, instr, simbuf, out);
}